// Round 1
// baseline (1211.856 us; speedup 1.0000x reference)
//
#include <hip/hip_runtime.h>

#define NROWS 16384
#define DIM   512
#define KC    8192
#define BM    64
#define NT_TILES 16          // K tiles of 512 codes
#define QCAP  32768
#define MARGIN 0.05f
#define LN2   0.69314718055994531f

typedef _Float16 half8  __attribute__((ext_vector_type(8)));
typedef _Float16 half4v __attribute__((ext_vector_type(4)));
typedef float    f32x4  __attribute__((ext_vector_type(4)));

#define MFMA(a,b,c) __builtin_amdgcn_mfma_f32_16x16x32_f16(a,b,c,0,0,0)

__device__ __forceinline__ float flog2(float x){ return __builtin_amdgcn_logf(x); }
__device__ __forceinline__ float fexp2(float x){ return __builtin_amdgcn_exp2f(x); }

__device__ __forceinline__ void top2_merge(float& v1, int& i1, float& v2, int& i2,
                                           float bv1, int bi1, float bv2, int bi2) {
  bool takeB = (bv1 > v1) || (bv1 == v1 && bi1 < i1);
  float nv1 = takeB ? bv1 : v1; int ni1 = takeB ? bi1 : i1;
  float cv  = takeB ? v1  : bv1; int ci = takeB ? i1  : bi1;  // loser's best
  float ov2 = takeB ? bv2 : v2;  int oi = takeB ? bi2 : i2;   // winner's 2nd
  bool cb = (cv > ov2) || (cv == ov2 && ci < oi);
  v2 = cb ? cv : ov2; i2 = cb ? ci : oi;
  v1 = nv1; i1 = ni1;
}

// ---------------- prep kernels ----------------
__global__ void prep_x(const float* __restrict__ x, _Float16* __restrict__ xh) {
  size_t i = (size_t)(blockIdx.x * blockDim.x + threadIdx.x) * 4;
  f32x4 v = *(const f32x4*)(x + i);
  half4v h;
  h[0] = (_Float16)(2.0f * v[0]); h[1] = (_Float16)(2.0f * v[1]);
  h[2] = (_Float16)(2.0f * v[2]); h[3] = (_Float16)(2.0f * v[3]);
  *(half4v*)(xh + i) = h;
}

__global__ void prep_c(const float* __restrict__ c, _Float16* __restrict__ ch) {
  size_t i = (size_t)(blockIdx.x * blockDim.x + threadIdx.x) * 4;
  f32x4 v = *(const f32x4*)(c + i);
  half4v h;
  h[0] = (_Float16)v[0]; h[1] = (_Float16)v[1];
  h[2] = (_Float16)v[2]; h[3] = (_Float16)v[3];
  *(half4v*)(ch + i) = h;
}

// transpose codebook -> ct[d][k] f16
__global__ void prep_ct(const float* __restrict__ c, _Float16* __restrict__ ct) {
  __shared__ _Float16 lt[64][72];
  const int kb = (blockIdx.x >> 3) * 64;
  const int db = (blockIdx.x & 7) * 64;
  {
    const int r = threadIdx.x >> 2, cs = threadIdx.x & 3;
#pragma unroll
    for (int j = 0; j < 4; ++j) {
      f32x4 v = *(const f32x4*)(c + (size_t)(kb + r) * DIM + db + cs * 16 + j * 4);
#pragma unroll
      for (int q = 0; q < 4; ++q) lt[r][cs * 16 + j * 4 + q] = (_Float16)v[q];
    }
  }
  __syncthreads();
  {
    const int d = threadIdx.x >> 2, ks = threadIdx.x & 3;
    half8 o0, o1;
#pragma unroll
    for (int j = 0; j < 8; ++j) { o0[j] = lt[ks * 16 + j][d]; o1[j] = lt[ks * 16 + 8 + j][d]; }
    _Float16* dst = ct + (size_t)(db + d) * KC + kb + ks * 16;
    *(half8*)dst = o0;
    *(half8*)(dst + 8) = o1;
  }
}

__global__ void prep_c2(const float* __restrict__ c, float* __restrict__ c2) {
  const int w = threadIdx.x >> 6, l = threadIdx.x & 63;
  const int code = blockIdx.x * 4 + w;
  double s = 0.0;
  for (int i = l; i < DIM; i += 64) { double v = c[(size_t)code * DIM + i]; s += v * v; }
#pragma unroll
  for (int o = 32; o; o >>= 1) s += __shfl_down(s, o, 64);
  if (l == 0) c2[code] = (float)s;
}

// ---------------- main fused kernel ----------------
// 256 blocks x 512 threads; block handles 64 rows; dynamic LDS 64KB = swizzled p[64][512] f16
__global__ __launch_bounds__(512, 2) void vq_fused(
    const float* __restrict__ U, const _Float16* __restrict__ Xh,
    const _Float16* __restrict__ Ch, const _Float16* __restrict__ CT,
    const float* __restrict__ C2, const float* __restrict__ Tp,
    float* __restrict__ emb, float* __restrict__ ids,
    int* __restrict__ fixcnt, int* __restrict__ fixq) {
  extern __shared__ char smem[];
  const int tid = threadIdx.x;
  const int w = tid >> 6, l = tid & 63;
  const int l15 = l & 15, l4 = l >> 4;
  const int row0 = blockIdx.x * BM;
  const float c1 = 1.4426950408889634f / Tp[0];   // log2e / T

  const _Float16* aptr[4];  // QK A: codes (swapped: S^T = C * X^T)
  const _Float16* xptr[4];  // QK B: x rows
  const _Float16* vptr[4];  // PV B: c^T rows (d-major)
  const float*    uptr[4];  // gumbel
#pragma unroll
  for (int i = 0; i < 4; ++i) {
    aptr[i] = Ch + (size_t)(w * 64 + 16 * i + l15) * DIM + l4 * 8;
    xptr[i] = Xh + (size_t)(row0 + l15 + 16 * i) * DIM + l4 * 8;
    vptr[i] = CT + (size_t)(w * 64 + 16 * i + l15) * KC + l4 * 8;
    uptr[i] = U  + (size_t)(row0 + l15 + 16 * i) * KC + w * 64 + l4 * 4;
  }
  const float* c2p = C2 + w * 64 + l4 * 4;

  // p-lds read bases (PV A operand), XOR-swizzled units of 16B
  int pbase[4], pxor[4];
#pragma unroll
  for (int rt = 0; rt < 4; ++rt) {
    int rw = l15 + 16 * rt;
    pbase[rt] = (rw << 10) + ((l4 ^ (rw & 3)) << 4);
    pxor[rt] = ((rw >> 2) & 1) << 6;
  }

  f32x4 O[4][4];   // [rt][dt]: rows x d-slice accumulator
#pragma unroll
  for (int a = 0; a < 4; ++a)
#pragma unroll
    for (int b = 0; b < 4; ++b) { O[a][b][0] = 0.f; O[a][b][1] = 0.f; O[a][b][2] = 0.f; O[a][b][3] = 0.f; }

  float m_run[4] = {-3e38f, -3e38f, -3e38f, -3e38f};
  float l_run[4] = {0.f, 0.f, 0.f, 0.f};
  float v1[4] = {-3e38f, -3e38f, -3e38f, -3e38f}, v2[4] = {-3e38f, -3e38f, -3e38f, -3e38f};
  int i1[4] = {0, 0, 0, 0}, i2[4] = {0, 0, 0, 0};

  float* mtab = (float*)smem;   // aliased: [8][64], consumed before p rows 0-1 written

#pragma unroll 1
  for (int t = 0; t < NT_TILES; ++t) {
    const size_t tA = (size_t)t * 512 * DIM;

    // ---- QK^T (swapped): acc[ct][nt] = S^T tile [16 codes][16 rows] ----
    f32x4 acc[4][4];
#pragma unroll
    for (int a = 0; a < 4; ++a)
#pragma unroll
      for (int b = 0; b < 4; ++b) { acc[a][b][0] = 0.f; acc[a][b][1] = 0.f; acc[a][b][2] = 0.f; acc[a][b][3] = 0.f; }
#pragma unroll
    for (int dc = 0; dc < 16; ++dc) {
      half8 b0 = *(const half8*)(xptr[0] + dc * 32);
      half8 b1 = *(const half8*)(xptr[1] + dc * 32);
      half8 b2 = *(const half8*)(xptr[2] + dc * 32);
      half8 b3 = *(const half8*)(xptr[3] + dc * 32);
#pragma unroll
      for (int ct = 0; ct < 4; ++ct) {
        half8 a = *(const half8*)(aptr[ct] + tA + dc * 32);
        acc[ct][0] = MFMA(a, b0, acc[ct][0]);
        acc[ct][1] = MFMA(a, b1, acc[ct][1]);
        acc[ct][2] = MFMA(a, b2, acc[ct][2]);
        acc[ct][3] = MFMA(a, b3, acc[ct][3]);
      }
    }

    // ---- scores, top2 tracking, gumbel, z ----
    float mw[4] = {-3e38f, -3e38f, -3e38f, -3e38f};
#pragma unroll
    for (int ct = 0; ct < 4; ++ct) {
      const f32x4 c2v = *(const f32x4*)(c2p + t * 512 + 16 * ct);
      const int cbase = t * 512 + w * 64 + 16 * ct + l4 * 4;
#pragma unroll
      for (int nt = 0; nt < 4; ++nt) {
        const f32x4 uu = *(const f32x4*)(uptr[nt] + t * 512 + 16 * ct);
        f32x4 zz;
#pragma unroll
        for (int r = 0; r < 4; ++r) {
          float s = acc[ct][nt][r] - c2v[r];          // 2 x.c - |c|^2  (x^2 row-const dropped)
          if (s > v1[nt]) { v2[nt] = v1[nt]; i2[nt] = i1[nt]; v1[nt] = s; i1[nt] = cbase + r; }
          else if (s > v2[nt]) { v2[nt] = s; i2[nt] = cbase + r; }
          float li = flog2(uu[r] + 1e-10f);
          float y  = fmaf(li, -LN2, 1e-10f);          // -log(u+eps)+eps
          float g  = flog2(y) * (-LN2);               // -log(y)
          float z  = (s + g) * c1;                    // log2-domain, /T folded
          zz[r] = z;
          mw[nt] = fmaxf(mw[nt], z);
        }
        acc[ct][nt] = zz;
      }
    }
    // wave row-max across the 4 lane-groups
#pragma unroll
    for (int nt = 0; nt < 4; ++nt) {
      mw[nt] = fmaxf(mw[nt], __shfl_xor(mw[nt], 16, 64));
      mw[nt] = fmaxf(mw[nt], __shfl_xor(mw[nt], 32, 64));
    }
    if (l < 16) {
#pragma unroll
      for (int nt = 0; nt < 4; ++nt) mtab[w * 64 + 16 * nt + l] = mw[nt];
    }
    __syncthreads();
    float alpha[4];
#pragma unroll
    for (int nt = 0; nt < 4; ++nt) {
      float mt = mtab[16 * nt + l15];
#pragma unroll
      for (int w2 = 1; w2 < 8; ++w2) mt = fmaxf(mt, mtab[w2 * 64 + 16 * nt + l15]);
      float mn = fmaxf(m_run[nt], mt);
      alpha[nt] = fexp2(m_run[nt] - mn);
      m_run[nt] = mn;
    }
    __syncthreads();   // mtab consumed -> p region writable

    // ---- p = exp2(z - m), write swizzled p-lds, accumulate l ----
    float lsum[4] = {0.f, 0.f, 0.f, 0.f};
#pragma unroll
    for (int ct = 0; ct < 4; ++ct) {
#pragma unroll
      for (int nt = 0; nt < 4; ++nt) {
        const int rw = l15 + 16 * nt;
        f32x4 zz = acc[ct][nt];
        float p0 = fexp2(zz[0] - m_run[nt]);
        float p1 = fexp2(zz[1] - m_run[nt]);
        float p2 = fexp2(zz[2] - m_run[nt]);
        float p3 = fexp2(zz[3] - m_run[nt]);
        lsum[nt] += (p0 + p1) + (p2 + p3);
        int unit = (w << 3) + (ct << 1) + (l4 >> 1);
        int off = (rw << 10) + ((unit ^ (rw & 7)) << 4) + ((l4 & 1) << 3);
        union { _Float16 h[2]; unsigned u; } pk;
        pk.h[0] = (_Float16)p0; pk.h[1] = (_Float16)p1;
        *(unsigned*)(smem + off) = pk.u;
        pk.h[0] = (_Float16)p2; pk.h[1] = (_Float16)p3;
        *(unsigned*)(smem + off + 4) = pk.u;
      }
    }
#pragma unroll
    for (int nt = 0; nt < 4; ++nt) {
      float s = lsum[nt];
      s += __shfl_xor(s, 16, 64);
      s += __shfl_xor(s, 32, 64);
      l_run[nt] = l_run[nt] * alpha[nt] + s;
    }
    // rescale O by alpha broadcast to O's row layout
#pragma unroll
    for (int rt = 0; rt < 4; ++rt) {
#pragma unroll
      for (int r = 0; r < 4; ++r) {
        float av = __shfl(alpha[rt], (l4 * 4 + r) & 15, 64);
#pragma unroll
        for (int dt = 0; dt < 4; ++dt) O[rt][dt][r] *= av;
      }
    }
    __syncthreads();   // p ready

    // ---- PV: O[rows][d-slice] += P[rows][512] * C[512][d] ----
#pragma unroll
    for (int kk = 0; kk < 16; ++kk) {
      half8 pa0 = *(const half8*)(smem + pbase[0] + (((kk << 6)) ^ pxor[0]));
      half8 pa1 = *(const half8*)(smem + pbase[1] + (((kk << 6)) ^ pxor[1]));
      half8 pa2 = *(const half8*)(smem + pbase[2] + (((kk << 6)) ^ pxor[2]));
      half8 pa3 = *(const half8*)(smem + pbase[3] + (((kk << 6)) ^ pxor[3]));
#pragma unroll
      for (int dt = 0; dt < 4; ++dt) {
        half8 bv = *(const half8*)(vptr[dt] + t * 512 + kk * 32);
        O[0][dt] = MFMA(pa0, bv, O[0][dt]);
        O[1][dt] = MFMA(pa1, bv, O[1][dt]);
        O[2][dt] = MFMA(pa2, bv, O[2][dt]);
        O[3][dt] = MFMA(pa3, bv, O[3][dt]);
      }
    }
    __syncthreads();   // all p reads done before next tile's mtab writes
  }

  // ================= epilogue =================
  float* ltab = (float*)smem;            // [8][64]
  float* fin  = (float*)(smem + 2048);   // [64] 1/l
  f32x4* atab = (f32x4*)(smem + 4096);   // [8][64] (v1, i1, v2, i2)

  if (l < 16) {
#pragma unroll
    for (int nt = 0; nt < 4; ++nt) ltab[w * 64 + 16 * nt + l] = l_run[nt];
  }
  __syncthreads();
  if (w == 0) {
    float s = 0.f;
#pragma unroll
    for (int w2 = 0; w2 < 8; ++w2) s += ltab[w2 * 64 + l];
    fin[l] = 1.0f / s;
  }
  __syncthreads();

#pragma unroll
  for (int rt = 0; rt < 4; ++rt) {
#pragma unroll
    for (int r = 0; r < 4; ++r) {
      const int row = l4 * 4 + r + 16 * rt;
      const float iv = fin[row];
      float* erow = emb + (size_t)(row0 + row) * DIM + w * 64 + l15;
#pragma unroll
      for (int dt = 0; dt < 4; ++dt) erow[16 * dt] = O[rt][dt][r] * iv;
    }
  }

  // argmax: wave-level merge then cross-wave via LDS
#pragma unroll
  for (int nt = 0; nt < 4; ++nt) {
    float bv1 = __shfl_xor(v1[nt], 16, 64); int bi1 = __shfl_xor(i1[nt], 16, 64);
    float bv2 = __shfl_xor(v2[nt], 16, 64); int bi2 = __shfl_xor(i2[nt], 16, 64);
    top2_merge(v1[nt], i1[nt], v2[nt], i2[nt], bv1, bi1, bv2, bi2);
    bv1 = __shfl_xor(v1[nt], 32, 64); bi1 = __shfl_xor(i1[nt], 32, 64);
    bv2 = __shfl_xor(v2[nt], 32, 64); bi2 = __shfl_xor(i2[nt], 32, 64);
    top2_merge(v1[nt], i1[nt], v2[nt], i2[nt], bv1, bi1, bv2, bi2);
  }
  if (l < 16) {
#pragma unroll
    for (int nt = 0; nt < 4; ++nt) {
      f32x4 pk;
      pk[0] = v1[nt]; pk[1] = __int_as_float(i1[nt]);
      pk[2] = v2[nt]; pk[3] = __int_as_float(i2[nt]);
      atab[w * 64 + 16 * nt + l] = pk;
    }
  }
  __syncthreads();
  if (w == 0) {
    f32x4 t0 = atab[l];
    float V1 = t0[0], V2 = t0[2];
    int I1 = __float_as_int(t0[1]), I2 = __float_as_int(t0[3]);
#pragma unroll
    for (int w2 = 1; w2 < 8; ++w2) {
      f32x4 tt = atab[w2 * 64 + l];
      top2_merge(V1, I1, V2, I2, tt[0], __float_as_int(tt[1]), tt[2], __float_as_int(tt[3]));
    }
    ids[row0 + l] = (float)I1;                 // provisional (exact unless near-tie)
    if (V1 - V2 <= MARGIN) {
      int qi = atomicAdd(fixcnt, 1);
      if (qi < QCAP) { fixq[qi * 3] = row0 + l; fixq[qi * 3 + 1] = I1; fixq[qi * 3 + 2] = I2; }
    }
  }
}

// exact rescoring of flagged near-ties (f64)
__global__ void vq_fixup(const float* __restrict__ X, const float* __restrict__ C,
                         const int* __restrict__ fixcnt, const int* __restrict__ fixq,
                         float* __restrict__ ids) {
  const int nw = (gridDim.x * blockDim.x) >> 6;
  const int gw = (blockIdx.x * blockDim.x + threadIdx.x) >> 6;
  const int l = threadIdx.x & 63;
  int cnt = *fixcnt; if (cnt > QCAP) cnt = QCAP;
  for (int q = gw; q < cnt; q += nw) {
    const int row = fixq[q * 3], a = fixq[q * 3 + 1], b = fixq[q * 3 + 2];
    double da = 0, ca = 0, db = 0, cb = 0;
    for (int i = l; i < DIM; i += 64) {
      double xv = X[(size_t)row * DIM + i];
      double av = C[(size_t)a * DIM + i];
      double bv = C[(size_t)b * DIM + i];
      da += xv * av; ca += av * av;
      db += xv * bv; cb += bv * bv;
    }
#pragma unroll
    for (int o = 32; o; o >>= 1) {
      da += __shfl_down(da, o, 64); ca += __shfl_down(ca, o, 64);
      db += __shfl_down(db, o, 64); cb += __shfl_down(cb, o, 64);
    }
    if (l == 0) {
      double sa = 2.0 * da - ca, sb = 2.0 * db - cb;
      int win = (sb > sa || (sb == sa && b < a)) ? b : a;
      ids[row] = (float)win;
    }
  }
}

extern "C" void kernel_launch(void* const* d_in, const int* in_sizes, int n_in,
                              void* d_out, int out_size, void* d_ws, size_t ws_size,
                              hipStream_t stream) {
  (void)in_sizes; (void)n_in; (void)out_size; (void)ws_size;
  const float* x  = (const float*)d_in[0];
  const float* cb = (const float*)d_in[1];
  const float* u  = (const float*)d_in[2];
  const float* tp = (const float*)d_in[3];
  float* emb = (float*)d_out;
  float* ids = emb + (size_t)NROWS * DIM;

  char* ws = (char*)d_ws;
  int* fixcnt = (int*)ws;
  int* fixq = (int*)(ws + 256);
  size_t off = (256 + (size_t)QCAP * 12 + 511) & ~(size_t)511;
  _Float16* xh = (_Float16*)(ws + off); off += (size_t)NROWS * DIM * 2;
  _Float16* ch = (_Float16*)(ws + off); off += (size_t)KC * DIM * 2;
  _Float16* ct = (_Float16*)(ws + off); off += (size_t)DIM * KC * 2;
  float* c2 = (float*)(ws + off);

  hipMemsetAsync(fixcnt, 0, 4, stream);
  prep_x <<<(NROWS * DIM) / 1024, 256, 0, stream>>>(x, xh);
  prep_c <<<(KC * DIM) / 1024, 256, 0, stream>>>(cb, ch);
  prep_ct<<<(KC / 64) * (DIM / 64), 256, 0, stream>>>(cb, ct);
  prep_c2<<<KC / 4, 256, 0, stream>>>(cb, c2);
  vq_fused<<<NROWS / BM, 512, 65536, stream>>>(u, xh, ch, ct, c2, tp, emb, ids, fixcnt, fixq);
  vq_fixup<<<32, 256, 0, stream>>>(x, cb, fixcnt, fixq, ids);
}